// Round 5
// baseline (527.720 us; speedup 1.0000x reference)
//
#include <hip/hip_runtime.h>
#include <hip/hip_bf16.h>

// Edgedropping: per-edge MLP score -> sigmoid -> global min/max normalize ->
// mask -> stable stream compaction of edge_index (2 rows) + edge_weight (14 rows).
// Output buffer: float32.
// R4 lesson: compiler capped VGPR at 64 (occupancy heuristic) and spilled
// wa/wb -> 1.05 GB scratch writes. Fix: __launch_bounds__(256,4) -> 128 VGPR.

constexpr int BLOCK = 256;
constexpr int CHUNK = 4096;            // edges per count/scatter chunk
constexpr int ROUNDS = CHUNK / BLOCK;  // 16

// ---- scoring (all-constant indexing; numerics identical to R3/R4 pass) -----
__device__ __forceinline__ float score14(const float (&we)[14],
                                         const float* sW1, const float* sb1,
                                         const float* sW2,
                                         float b2, float rlog) {
    double acc2 = 0.0;
#pragma unroll
    for (int k = 0; k < 7; ++k) {
        double a = 0.0;
#pragma unroll
        for (int j = 0; j < 14; ++j) a += (double)we[j] * (double)sW1[k * 14 + j];
        float hp = __fadd_rn((float)a, sb1[k]);
        hp = fmaxf(hp, 0.0f);
        acc2 += (double)hp * (double)sW2[k];
    }
    float raw = __fadd_rn((float)acc2, b2);
    float z = __fdiv_rn(__fadd_rn(rlog, raw), 0.05f);
    return __fdiv_rn(1.0f, __fadd_rn(1.0f, expf(-z)));
}

__device__ __forceinline__ bool mask_of(float s, float vmin, float range) {
    float t = __fdiv_rn(__fsub_rn(s, vmin), range);
    float sn = __fadd_rn(__fmul_rn(t, 1.2f), -0.1f);
    return sn > 0.0f;
}

// ---- kernels ---------------------------------------------------------------

__global__ void k_init(unsigned int* minmax) {
    minmax[0] = 0x7F800000u;  // +inf (s>=0 so uint order == float order)
    minmax[1] = 0x00000000u;
}

__global__ __launch_bounds__(256, 4)
void k_compute_s(const float* __restrict__ ew,
                 const float* __restrict__ W1, const float* __restrict__ b1,
                 const float* __restrict__ W2, const float* __restrict__ b2,
                 const float* __restrict__ rl,
                 float* __restrict__ s_out,
                 unsigned int* __restrict__ minmax,
                 long long E) {
    __shared__ float sW1[98], sb1[7], sW2[7];
    __shared__ float sb2, srl;
    int tid = threadIdx.x;
    if (tid < 98) sW1[tid] = W1[tid];
    if (tid < 7) { sb1[tid] = b1[tid]; sW2[tid] = W2[tid]; }
    if (tid == 0) { sb2 = b2[0]; srl = rl[0]; }
    __syncthreads();

    long long nPairs = (E + 1) / 2;
    long long i = (long long)blockIdx.x * blockDim.x + tid;
    float lmin = __uint_as_float(0x7F800000u), lmax = 0.0f;

    if (i < nPairs) {
        float wa[14], wb[14];
        bool have2 = (2 * i + 1 < E);
        if (have2) {
            const float4* p = (const float4*)ew + (size_t)i * 7;  // 112B stride, 16B-aligned
#pragma unroll
            for (int q = 0; q < 7; ++q) {
                float4 v = p[q];
#pragma unroll
                for (int r = 0; r < 4; ++r) {
                    float f = (r == 0) ? v.x : (r == 1) ? v.y : (r == 2) ? v.z : v.w;
                    int g = 4 * q + r;
                    if (g < 14) wa[g] = f; else wb[g - 14] = f;
                }
            }
        } else {
            const float* p = ew + (size_t)(2 * i) * 14;
#pragma unroll
            for (int j = 0; j < 14; ++j) { wa[j] = p[j]; wb[j] = 0.0f; }
        }
        float s0 = score14(wa, sW1, sb1, sW2, sb2, srl);
        lmin = fminf(lmin, s0);
        lmax = fmaxf(lmax, s0);
        if (have2) {
            float s1 = score14(wb, sW1, sb1, sW2, sb2, srl);
            lmin = fminf(lmin, s1);
            lmax = fmaxf(lmax, s1);
            float2 st; st.x = s0; st.y = s1;
            *(float2*)(s_out + 2 * i) = st;   // 8B-aligned coalesced
        } else {
            s_out[2 * i] = s0;
        }
    }
#pragma unroll
    for (int off = 32; off; off >>= 1) {
        lmin = fminf(lmin, __shfl_down(lmin, off));
        lmax = fmaxf(lmax, __shfl_down(lmax, off));
    }
    __shared__ float wmin[4], wmax[4];
    int lane = tid & 63, wid = tid >> 6;
    if (lane == 0) { wmin[wid] = lmin; wmax[wid] = lmax; }
    __syncthreads();
    if (tid == 0) {
        float m0 = wmin[0], M0 = wmax[0];
#pragma unroll
        for (int q = 1; q < 4; ++q) { m0 = fminf(m0, wmin[q]); M0 = fmaxf(M0, wmax[q]); }
        atomicMin(&minmax[0], __float_as_uint(m0));
        atomicMax(&minmax[1], __float_as_uint(M0));
    }
}

__global__ void k_count(const float* __restrict__ s_arr,
                        const unsigned int* __restrict__ minmax,
                        int* __restrict__ counts, long long E) {
    int chunk = blockIdx.x;
    long long base = (long long)chunk * CHUNK;
    float vmin = __uint_as_float(minmax[0]);
    float vmax = __uint_as_float(minmax[1]);
    float range = __fsub_rn(vmax, vmin);
    int tid = threadIdx.x;
    int cnt = 0;
#pragma unroll
    for (int r = 0; r < ROUNDS; ++r) {
        long long e = base + r * BLOCK + tid;
        if (e < E) cnt += mask_of(s_arr[e], vmin, range) ? 1 : 0;
    }
#pragma unroll
    for (int off = 32; off; off >>= 1) cnt += __shfl_down(cnt, off);
    __shared__ int wc[4];
    if ((tid & 63) == 0) wc[tid >> 6] = cnt;
    __syncthreads();
    if (tid == 0) counts[chunk] = wc[0] + wc[1] + wc[2] + wc[3];
}

// single block, 1024 threads, LDS Hillis-Steele; requires nchunks <= 1024
__global__ void k_scan(const int* __restrict__ counts, int* __restrict__ offsets,
                       int nchunks) {
    __shared__ int tmp[1024];
    int tid = threadIdx.x;
    int v = (tid < nchunks) ? counts[tid] : 0;
    tmp[tid] = v;
    for (int off = 1; off < 1024; off <<= 1) {
        __syncthreads();
        int y = (tid >= off) ? tmp[tid - off] : 0;
        __syncthreads();
        tmp[tid] += y;
    }
    if (tid < nchunks) offsets[tid] = tmp[tid] - v;   // exclusive prefix
}

__global__ void k_scatter(const float* __restrict__ s_arr,
                          const unsigned int* __restrict__ minmax,
                          const int* __restrict__ offsets,
                          const int* __restrict__ ei,
                          const float* __restrict__ ew,
                          float* __restrict__ out,
                          long long E, int K) {
    int chunk = blockIdx.x;
    long long base = (long long)chunk * CHUNK;
    int tid = threadIdx.x, lane = tid & 63, wid = tid >> 6;
    float vmin = __uint_as_float(minmax[0]);
    float vmax = __uint_as_float(minmax[1]);
    float range = __fsub_rn(vmax, vmin);

    __shared__ int cnt_rw[ROUNDS][4];
    __shared__ int off_rw[ROUNDS][4];

    // pass 1: per-(round,wave) mask counts
    for (int r = 0; r < ROUNDS; ++r) {
        long long e = base + r * BLOCK + tid;
        bool m = (e < E) && mask_of(s_arr[e], vmin, range);
        unsigned long long bal = __ballot(m);
        if (lane == 0) cnt_rw[r][wid] = (int)__popcll(bal);
    }
    __syncthreads();
    if (tid == 0) {
        int run = 0;
        for (int r = 0; r < ROUNDS; ++r)
            for (int w = 0; w < 4; ++w) { off_rw[r][w] = run; run += cnt_rw[r][w]; }
    }
    __syncthreads();

    int chunk_base = offsets[chunk];
    unsigned long long lt = (lane == 0) ? 0ull : ((1ull << lane) - 1ull);

    // pass 2: write
    for (int r = 0; r < ROUNDS; ++r) {
        long long e = base + r * BLOCK + tid;
        bool m = (e < E) && mask_of(s_arr[e], vmin, range);
        unsigned long long bal = __ballot(m);
        int myrank = __popcll(bal & lt);
        if (m) {
            long long posl = (long long)chunk_base + off_rw[r][wid] + myrank;
            if (posl >= 0 && posl < (long long)K) {
                size_t pos = (size_t)posl;
                size_t Ks = (size_t)K;
                out[pos]      = (float)ei[e];
                out[Ks + pos] = (float)ei[E + e];
#pragma unroll
                for (int rr = 0; rr < 14; ++rr)
                    out[(size_t)(2 + rr) * Ks + pos] = ew[(size_t)rr * E + e];
            }
        }
    }
}

// ---- launch ----------------------------------------------------------------

extern "C" void kernel_launch(void* const* d_in, const int* in_sizes, int n_in,
                              void* d_out, int out_size, void* d_ws, size_t ws_size,
                              hipStream_t stream) {
    const int*   ei = (const int*)d_in[1];
    const float* ew = (const float*)d_in[2];
    const float* W1 = (const float*)d_in[3];
    const float* b1 = (const float*)d_in[4];
    const float* W2 = (const float*)d_in[5];
    const float* b2 = (const float*)d_in[6];
    const float* rl = (const float*)d_in[7];

    long long E = (long long)in_sizes[2] / 14;
    int K = out_size / 16;
    int nchunks = (int)((E + CHUNK - 1) / CHUNK);

    char* ws = (char*)d_ws;
    float*        s_arr   = (float*)ws;
    unsigned int* minmax  = (unsigned int*)(ws + (size_t)E * 4);
    int*          counts  = (int*)(ws + (size_t)E * 4 + 2 * sizeof(unsigned int));
    int*          offsets = counts + nchunks;

    float* out = (float*)d_out;

    k_init<<<1, 1, 0, stream>>>(minmax);

    long long nPairs = (E + 1) / 2;
    int g1 = (int)((nPairs + BLOCK - 1) / BLOCK);
    k_compute_s<<<g1, BLOCK, 0, stream>>>(ew, W1, b1, W2, b2, rl, s_arr, minmax, E);

    k_count<<<nchunks, BLOCK, 0, stream>>>(s_arr, minmax, counts, E);
    k_scan<<<1, 1024, 0, stream>>>(counts, offsets, nchunks);
    k_scatter<<<nchunks, BLOCK, 0, stream>>>(s_arr, minmax, offsets, ei, ew, out, E, K);
}

// Round 6
// 485.430 us; speedup vs baseline: 1.0871x; 1.0871x over previous
//
#include <hip/hip_runtime.h>
#include <hip/hip_bf16.h>

// Edgedropping: per-edge MLP score -> sigmoid -> global min/max normalize ->
// mask -> stable stream compaction of edge_index (2 rows) + edge_weight (14 rows).
// Output buffer: float32.
// R5 lesson: regalloc insists on 64 VGPR and spills per-thread feature arrays
// (~1 GB scratch). Fix: features via LDS tile (stride 15, conflict-free),
// weights as f64 via uniform scalar loads; 7 named f64 accumulators only.
// Numerics bit-identical to the R3-passing version (same op order/rounding).

constexpr int BLOCK = 256;
constexpr int CHUNK = 4096;            // edges per count/scatter chunk
constexpr int ROUNDS = CHUNK / BLOCK;  // 16
constexpr int TS = 15;                 // LDS tile stride (pad 14 -> 15)

__device__ __forceinline__ bool mask_of(float s, float vmin, float range) {
    float t = __fdiv_rn(__fsub_rn(s, vmin), range);
    float sn = __fadd_rn(__fmul_rn(t, 1.2f), -0.1f);
    return sn > 0.0f;
}

// ---- kernels ---------------------------------------------------------------

__global__ void k_init(unsigned int* minmax) {
    minmax[0] = 0x7F800000u;  // +inf (s>=0 so uint order == float order)
    minmax[1] = 0x00000000u;
}

// promote W1, W2 to f64 once (uniform scalar-load source for main kernel)
__global__ void k_prep(const float* __restrict__ W1, const float* __restrict__ W2,
                       double* __restrict__ W1d, double* __restrict__ W2d) {
    int i = threadIdx.x;
    if (i < 98) W1d[i] = (double)W1[i];
    if (i < 7)  W2d[i] = (double)W2[i];
}

__global__ void k_compute_s(const float* __restrict__ ew,
                            const double* __restrict__ W1d,
                            const float* __restrict__ b1,
                            const double* __restrict__ W2d,
                            const float* __restrict__ b2,
                            const float* __restrict__ rl,
                            float* __restrict__ s_out,
                            unsigned int* __restrict__ minmax,
                            long long E) {
    __shared__ float tile[BLOCK * TS];
    int tid = threadIdx.x;
    long long base = (long long)blockIdx.x * BLOCK;
    int nE_blk = (int)((E - base < BLOCK) ? (E - base) : BLOCK);

    // coalesced float4 staging: block's features are contiguous [base*14, ..)
    {
        int elems = nE_blk * 14;
        int nf4 = elems >> 2;
        const float4* gp = (const float4*)(ew + base * 14);   // base*14 % 4 == 0
        for (int v = tid; v < nf4; v += BLOCK) {
            float4 f = gp[v];
#pragma unroll
            for (int r = 0; r < 4; ++r) {
                float val = (r == 0) ? f.x : (r == 1) ? f.y : (r == 2) ? f.z : f.w;
                int g = 4 * v + r;
                tile[(g / 14) * TS + (g % 14)] = val;
            }
        }
        int rem = elems & 3;
        if (tid < rem) {
            int g = (nf4 << 2) + tid;
            tile[(g / 14) * TS + (g % 14)] = ew[base * 14 + g];
        }
    }
    __syncthreads();

    float lmin = __uint_as_float(0x7F800000u), lmax = 0.0f;
    bool active = (tid < nE_blk);
    if (active) {
        // layer 1: 7 f64 dot-products, j-outer (same per-k accumulation order)
        double a0 = 0.0, a1 = 0.0, a2 = 0.0, a3 = 0.0, a4 = 0.0, a5 = 0.0, a6 = 0.0;
        const float* fp = tile + tid * TS;
#pragma unroll
        for (int j = 0; j < 14; ++j) {
            double fd = (double)fp[j];
            a0 += fd * W1d[0 * 14 + j];
            a1 += fd * W1d[1 * 14 + j];
            a2 += fd * W1d[2 * 14 + j];
            a3 += fd * W1d[3 * 14 + j];
            a4 += fd * W1d[4 * 14 + j];
            a5 += fd * W1d[5 * 14 + j];
            a6 += fd * W1d[6 * 14 + j];
        }
        double acc2 = 0.0;
        {
            double aa[7] = {a0, a1, a2, a3, a4, a5, a6};
#pragma unroll
            for (int k = 0; k < 7; ++k) {
                float hp = __fadd_rn((float)aa[k], b1[k]);
                hp = fmaxf(hp, 0.0f);
                acc2 += (double)hp * W2d[k];
            }
        }
        float raw = __fadd_rn((float)acc2, b2[0]);
        float z = __fdiv_rn(__fadd_rn(rl[0], raw), 0.05f);
        float s = __fdiv_rn(1.0f, __fadd_rn(1.0f, expf(-z)));
        s_out[base + tid] = s;
        lmin = s;
        lmax = s;
    }
#pragma unroll
    for (int off = 32; off; off >>= 1) {
        lmin = fminf(lmin, __shfl_down(lmin, off));
        lmax = fmaxf(lmax, __shfl_down(lmax, off));
    }
    __shared__ float wmin[4], wmax[4];
    int lane = tid & 63, wid = tid >> 6;
    if (lane == 0) { wmin[wid] = lmin; wmax[wid] = lmax; }
    __syncthreads();
    if (tid == 0) {
        float m0 = wmin[0], M0 = wmax[0];
#pragma unroll
        for (int q = 1; q < 4; ++q) { m0 = fminf(m0, wmin[q]); M0 = fmaxf(M0, wmax[q]); }
        atomicMin(&minmax[0], __float_as_uint(m0));
        atomicMax(&minmax[1], __float_as_uint(M0));
    }
}

__global__ void k_count(const float* __restrict__ s_arr,
                        const unsigned int* __restrict__ minmax,
                        int* __restrict__ counts, long long E) {
    int chunk = blockIdx.x;
    long long base = (long long)chunk * CHUNK;
    float vmin = __uint_as_float(minmax[0]);
    float vmax = __uint_as_float(minmax[1]);
    float range = __fsub_rn(vmax, vmin);
    int tid = threadIdx.x;
    int cnt = 0;
#pragma unroll
    for (int r = 0; r < ROUNDS; ++r) {
        long long e = base + r * BLOCK + tid;
        if (e < E) cnt += mask_of(s_arr[e], vmin, range) ? 1 : 0;
    }
#pragma unroll
    for (int off = 32; off; off >>= 1) cnt += __shfl_down(cnt, off);
    __shared__ int wc[4];
    if ((tid & 63) == 0) wc[tid >> 6] = cnt;
    __syncthreads();
    if (tid == 0) counts[chunk] = wc[0] + wc[1] + wc[2] + wc[3];
}

// single block, 1024 threads, LDS Hillis-Steele; requires nchunks <= 1024
__global__ void k_scan(const int* __restrict__ counts, int* __restrict__ offsets,
                       int nchunks) {
    __shared__ int tmp[1024];
    int tid = threadIdx.x;
    int v = (tid < nchunks) ? counts[tid] : 0;
    tmp[tid] = v;
    for (int off = 1; off < 1024; off <<= 1) {
        __syncthreads();
        int y = (tid >= off) ? tmp[tid - off] : 0;
        __syncthreads();
        tmp[tid] += y;
    }
    if (tid < nchunks) offsets[tid] = tmp[tid] - v;   // exclusive prefix
}

__global__ void k_scatter(const float* __restrict__ s_arr,
                          const unsigned int* __restrict__ minmax,
                          const int* __restrict__ offsets,
                          const int* __restrict__ ei,
                          const float* __restrict__ ew,
                          float* __restrict__ out,
                          long long E, int K) {
    int chunk = blockIdx.x;
    long long base = (long long)chunk * CHUNK;
    int tid = threadIdx.x, lane = tid & 63, wid = tid >> 6;
    float vmin = __uint_as_float(minmax[0]);
    float vmax = __uint_as_float(minmax[1]);
    float range = __fsub_rn(vmax, vmin);

    __shared__ int cnt_rw[ROUNDS][4];
    __shared__ int off_rw[ROUNDS][4];

    // pass 1: per-(round,wave) mask counts
    for (int r = 0; r < ROUNDS; ++r) {
        long long e = base + r * BLOCK + tid;
        bool m = (e < E) && mask_of(s_arr[e], vmin, range);
        unsigned long long bal = __ballot(m);
        if (lane == 0) cnt_rw[r][wid] = (int)__popcll(bal);
    }
    __syncthreads();
    if (tid == 0) {
        int run = 0;
        for (int r = 0; r < ROUNDS; ++r)
            for (int w = 0; w < 4; ++w) { off_rw[r][w] = run; run += cnt_rw[r][w]; }
    }
    __syncthreads();

    int chunk_base = offsets[chunk];
    unsigned long long lt = (lane == 0) ? 0ull : ((1ull << lane) - 1ull);

    // pass 2: write
    for (int r = 0; r < ROUNDS; ++r) {
        long long e = base + r * BLOCK + tid;
        bool m = (e < E) && mask_of(s_arr[e], vmin, range);
        unsigned long long bal = __ballot(m);
        int myrank = __popcll(bal & lt);
        if (m) {
            long long posl = (long long)chunk_base + off_rw[r][wid] + myrank;
            if (posl >= 0 && posl < (long long)K) {
                size_t pos = (size_t)posl;
                size_t Ks = (size_t)K;
                out[pos]      = (float)ei[e];
                out[Ks + pos] = (float)ei[E + e];
#pragma unroll
                for (int rr = 0; rr < 14; ++rr)
                    out[(size_t)(2 + rr) * Ks + pos] = ew[(size_t)rr * E + e];
            }
        }
    }
}

// ---- launch ----------------------------------------------------------------

extern "C" void kernel_launch(void* const* d_in, const int* in_sizes, int n_in,
                              void* d_out, int out_size, void* d_ws, size_t ws_size,
                              hipStream_t stream) {
    const int*   ei = (const int*)d_in[1];
    const float* ew = (const float*)d_in[2];
    const float* W1 = (const float*)d_in[3];
    const float* b1 = (const float*)d_in[4];
    const float* W2 = (const float*)d_in[5];
    const float* b2 = (const float*)d_in[6];
    const float* rl = (const float*)d_in[7];

    long long E = (long long)in_sizes[2] / 14;
    int K = out_size / 16;
    int nchunks = (int)((E + CHUNK - 1) / CHUNK);

    // ws layout: [W1d 98*8][W2d 7*8] pad to 1024 | s_arr E*4 | minmax 8 | counts | offsets
    char* ws = (char*)d_ws;
    double*       W1d     = (double*)ws;
    double*       W2d     = W1d + 98;
    float*        s_arr   = (float*)(ws + 1024);
    unsigned int* minmax  = (unsigned int*)(ws + 1024 + (size_t)E * 4);
    int*          counts  = (int*)(ws + 1024 + (size_t)E * 4 + 8);
    int*          offsets = counts + nchunks;

    float* out = (float*)d_out;

    k_init<<<1, 1, 0, stream>>>(minmax);
    k_prep<<<1, 128, 0, stream>>>(W1, W2, W1d, W2d);

    int g1 = (int)((E + BLOCK - 1) / BLOCK);
    k_compute_s<<<g1, BLOCK, 0, stream>>>(ew, W1d, b1, W2d, b2, rl, s_arr, minmax, E);

    k_count<<<nchunks, BLOCK, 0, stream>>>(s_arr, minmax, counts, E);
    k_scan<<<1, 1024, 0, stream>>>(counts, offsets, nchunks);
    k_scatter<<<nchunks, BLOCK, 0, stream>>>(s_arr, minmax, offsets, ei, ew, out, E, K);
}

// Round 7
// 184.019 us; speedup vs baseline: 2.8678x; 2.6379x over previous
//
#include <hip/hip_runtime.h>
#include <hip/hip_bf16.h>

// Edgedropping: per-edge MLP score -> sigmoid -> global min/max normalize ->
// mask -> stable stream compaction of edge_index (2 rows) + edge_weight (14 rows).
// Output buffer: float32.
// R6 lesson: LDS-tile + f64-smem-weights version was latency-bound (VALUBusy 10%,
// VGPR 24, lgkmcnt chains + single-address atomics). R7: one edge/thread in
// registers (no spill at ~45 live VGPR), f64 weights in LDS (broadcast reads),
// per-block min/max partials + separate reduce kernel (no atomics).

constexpr int BLOCK = 256;
constexpr int CHUNK = 4096;            // edges per count/scatter chunk
constexpr int ROUNDS = CHUNK / BLOCK;  // 16

__device__ __forceinline__ bool mask_of(float s, float vmin, float range) {
    float t = __fdiv_rn(__fsub_rn(s, vmin), range);
    float sn = __fadd_rn(__fmul_rn(t, 1.2f), -0.1f);
    return sn > 0.0f;
}

// ---- kernels ---------------------------------------------------------------

__global__ void k_compute_s(const float* __restrict__ ew,
                            const float* __restrict__ W1, const float* __restrict__ b1,
                            const float* __restrict__ W2, const float* __restrict__ b2,
                            const float* __restrict__ rl,
                            float* __restrict__ s_out,
                            float2* __restrict__ partial,
                            long long E) {
    __shared__ double sW1d[98], sW2d[7];
    __shared__ float sb1[7];
    __shared__ float sb2, srl;
    int tid = threadIdx.x;
    if (tid < 98) sW1d[tid] = (double)W1[tid];
    if (tid < 7) { sW2d[tid] = (double)W2[tid]; sb1[tid] = b1[tid]; }
    if (tid == 0) { sb2 = b2[0]; srl = rl[0]; }
    __syncthreads();

    long long e = (long long)blockIdx.x * BLOCK + tid;
    float lmin = __uint_as_float(0x7F800000u), lmax = 0.0f;

    if (e < E) {
        const float2* p2 = (const float2*)ew + e * 7;   // e*56 B, 8B-aligned
        float2 q0 = p2[0], q1 = p2[1], q2 = p2[2], q3 = p2[3],
               q4 = p2[4], q5 = p2[5], q6 = p2[6];
        float w[14] = {q0.x, q0.y, q1.x, q1.y, q2.x, q2.y, q3.x, q3.y,
                       q4.x, q4.y, q5.x, q5.y, q6.x, q6.y};

        // layer 1: 7 f64 dots, j-outer (per-k accumulation order matches R3 pass)
        double a0 = 0.0, a1 = 0.0, a2 = 0.0, a3 = 0.0, a4 = 0.0, a5 = 0.0, a6 = 0.0;
#pragma unroll
        for (int j = 0; j < 14; ++j) {
            double fd = (double)w[j];
            a0 += fd * sW1d[0 * 14 + j];
            a1 += fd * sW1d[1 * 14 + j];
            a2 += fd * sW1d[2 * 14 + j];
            a3 += fd * sW1d[3 * 14 + j];
            a4 += fd * sW1d[4 * 14 + j];
            a5 += fd * sW1d[5 * 14 + j];
            a6 += fd * sW1d[6 * 14 + j];
        }
        // layer 2 (same rounding points as passed versions)
        double acc2 = 0.0;
#define L2STEP(kk, ak) { float hp = __fadd_rn((float)(ak), sb1[kk]); \
                         hp = fmaxf(hp, 0.0f); \
                         acc2 += (double)hp * sW2d[kk]; }
        L2STEP(0, a0) L2STEP(1, a1) L2STEP(2, a2) L2STEP(3, a3)
        L2STEP(4, a4) L2STEP(5, a5) L2STEP(6, a6)
#undef L2STEP
        float raw = __fadd_rn((float)acc2, sb2);
        float z = __fdiv_rn(__fadd_rn(srl, raw), 0.05f);
        float s = __fdiv_rn(1.0f, __fadd_rn(1.0f, expf(-z)));
        s_out[e] = s;
        lmin = s;
        lmax = s;
    }
#pragma unroll
    for (int off = 32; off; off >>= 1) {
        lmin = fminf(lmin, __shfl_down(lmin, off));
        lmax = fmaxf(lmax, __shfl_down(lmax, off));
    }
    __shared__ float wmn[4], wmx[4];
    int lane = tid & 63, wid = tid >> 6;
    if (lane == 0) { wmn[wid] = lmin; wmx[wid] = lmax; }
    __syncthreads();
    if (tid == 0) {
        float m0 = wmn[0], M0 = wmx[0];
#pragma unroll
        for (int q = 1; q < 4; ++q) { m0 = fminf(m0, wmn[q]); M0 = fmaxf(M0, wmx[q]); }
        float2 pr; pr.x = m0; pr.y = M0;
        partial[blockIdx.x] = pr;
    }
}

// single block: reduce per-block partials -> mm[0]=vmin, mm[1]=vmax
__global__ void k_minmax(const float2* __restrict__ partial, int n,
                         float* __restrict__ mm) {
    int tid = threadIdx.x;
    float lmin = __uint_as_float(0x7F800000u), lmax = 0.0f;
    for (int i = tid; i < n; i += 1024) {
        float2 p = partial[i];
        lmin = fminf(lmin, p.x);
        lmax = fmaxf(lmax, p.y);
    }
#pragma unroll
    for (int off = 32; off; off >>= 1) {
        lmin = fminf(lmin, __shfl_down(lmin, off));
        lmax = fmaxf(lmax, __shfl_down(lmax, off));
    }
    __shared__ float wmn[16], wmx[16];
    int lane = tid & 63, wid = tid >> 6;
    if (lane == 0) { wmn[wid] = lmin; wmx[wid] = lmax; }
    __syncthreads();
    if (tid == 0) {
        float m = wmn[0], M = wmx[0];
#pragma unroll
        for (int q = 1; q < 16; ++q) { m = fminf(m, wmn[q]); M = fmaxf(M, wmx[q]); }
        mm[0] = m; mm[1] = M;
    }
}

__global__ void k_count(const float* __restrict__ s_arr,
                        const float* __restrict__ mm,
                        int* __restrict__ counts, long long E) {
    int chunk = blockIdx.x;
    long long base = (long long)chunk * CHUNK;
    float vmin = mm[0];
    float range = __fsub_rn(mm[1], vmin);
    int tid = threadIdx.x;
    int cnt = 0;
#pragma unroll
    for (int r = 0; r < ROUNDS; ++r) {
        long long e = base + r * BLOCK + tid;
        if (e < E) cnt += mask_of(s_arr[e], vmin, range) ? 1 : 0;
    }
#pragma unroll
    for (int off = 32; off; off >>= 1) cnt += __shfl_down(cnt, off);
    __shared__ int wc[4];
    if ((tid & 63) == 0) wc[tid >> 6] = cnt;
    __syncthreads();
    if (tid == 0) counts[chunk] = wc[0] + wc[1] + wc[2] + wc[3];
}

// single block, 1024 threads, LDS Hillis-Steele; requires nchunks <= 1024
__global__ void k_scan(const int* __restrict__ counts, int* __restrict__ offsets,
                       int nchunks) {
    __shared__ int tmp[1024];
    int tid = threadIdx.x;
    int v = (tid < nchunks) ? counts[tid] : 0;
    tmp[tid] = v;
    for (int off = 1; off < 1024; off <<= 1) {
        __syncthreads();
        int y = (tid >= off) ? tmp[tid - off] : 0;
        __syncthreads();
        tmp[tid] += y;
    }
    if (tid < nchunks) offsets[tid] = tmp[tid] - v;   // exclusive prefix
}

__global__ void k_scatter(const float* __restrict__ s_arr,
                          const float* __restrict__ mm,
                          const int* __restrict__ offsets,
                          const int* __restrict__ ei,
                          const float* __restrict__ ew,
                          float* __restrict__ out,
                          long long E, int K) {
    int chunk = blockIdx.x;
    long long base = (long long)chunk * CHUNK;
    int tid = threadIdx.x, lane = tid & 63, wid = tid >> 6;
    float vmin = mm[0];
    float range = __fsub_rn(mm[1], vmin);

    __shared__ int cnt_rw[ROUNDS][4];
    __shared__ int off_rw[ROUNDS][4];

    // pass 1: per-(round,wave) mask counts
    for (int r = 0; r < ROUNDS; ++r) {
        long long e = base + r * BLOCK + tid;
        bool m = (e < E) && mask_of(s_arr[e], vmin, range);
        unsigned long long bal = __ballot(m);
        if (lane == 0) cnt_rw[r][wid] = (int)__popcll(bal);
    }
    __syncthreads();
    if (tid == 0) {
        int run = 0;
        for (int r = 0; r < ROUNDS; ++r)
            for (int w = 0; w < 4; ++w) { off_rw[r][w] = run; run += cnt_rw[r][w]; }
    }
    __syncthreads();

    int chunk_base = offsets[chunk];
    unsigned long long lt = (lane == 0) ? 0ull : ((1ull << lane) - 1ull);

    // pass 2: write
    for (int r = 0; r < ROUNDS; ++r) {
        long long e = base + r * BLOCK + tid;
        bool m = (e < E) && mask_of(s_arr[e], vmin, range);
        unsigned long long bal = __ballot(m);
        int myrank = __popcll(bal & lt);
        if (m) {
            long long posl = (long long)chunk_base + off_rw[r][wid] + myrank;
            if (posl >= 0 && posl < (long long)K) {
                size_t pos = (size_t)posl;
                size_t Ks = (size_t)K;
                out[pos]      = (float)ei[e];
                out[Ks + pos] = (float)ei[E + e];
#pragma unroll
                for (int rr = 0; rr < 14; ++rr)
                    out[(size_t)(2 + rr) * Ks + pos] = ew[(size_t)rr * E + e];
            }
        }
    }
}

// ---- launch ----------------------------------------------------------------

extern "C" void kernel_launch(void* const* d_in, const int* in_sizes, int n_in,
                              void* d_out, int out_size, void* d_ws, size_t ws_size,
                              hipStream_t stream) {
    const int*   ei = (const int*)d_in[1];
    const float* ew = (const float*)d_in[2];
    const float* W1 = (const float*)d_in[3];
    const float* b1 = (const float*)d_in[4];
    const float* W2 = (const float*)d_in[5];
    const float* b2 = (const float*)d_in[6];
    const float* rl = (const float*)d_in[7];

    long long E = (long long)in_sizes[2] / 14;
    int K = out_size / 16;
    int nchunks = (int)((E + CHUNK - 1) / CHUNK);
    int nblocks = (int)((E + BLOCK - 1) / BLOCK);

    // ws: s_arr E*4 | partial nblocks*8 | mm 8B | counts | offsets
    char* ws = (char*)d_ws;
    float*  s_arr   = (float*)ws;
    float2* partial = (float2*)(ws + (size_t)E * 4);
    float*  mm      = (float*)(ws + (size_t)E * 4 + (size_t)nblocks * 8);
    int*    counts  = (int*)(ws + (size_t)E * 4 + (size_t)nblocks * 8 + 8);
    int*    offsets = counts + nchunks;

    float* out = (float*)d_out;

    k_compute_s<<<nblocks, BLOCK, 0, stream>>>(ew, W1, b1, W2, b2, rl,
                                               s_arr, partial, E);
    k_minmax<<<1, 1024, 0, stream>>>(partial, nblocks, mm);
    k_count<<<nchunks, BLOCK, 0, stream>>>(s_arr, mm, counts, E);
    k_scan<<<1, 1024, 0, stream>>>(counts, offsets, nchunks);
    k_scatter<<<nchunks, BLOCK, 0, stream>>>(s_arr, mm, offsets, ei, ew, out, E, K);
}